// Round 1
// baseline (103.903 us; speedup 1.0000x reference)
//
#include <hip/hip_runtime.h>
#include <math.h>

#define GDIM 640
#define NDIM 320
#define PADW 160
#define NB 8
#define NM 200000
#define PI_F 3.14159265358979323846f

// ---------- Bessel I0 (Abramowitz & Stegun 9.8.1/9.8.2, |err| < 2e-7) ----------
__device__ __forceinline__ float bessel_i0f(float x) {
    if (x < 3.75f) {
        float t = x * (1.0f / 3.75f);
        t *= t;
        return 1.0f + t * (3.5156229f + t * (3.0899424f + t * (1.2067492f +
                     t * (0.2659732f + t * (0.0360768f + t * 0.0045813f)))));
    }
    float t = 3.75f / x;
    float p = 0.39894228f + t * (0.01328592f + t * (0.00225319f + t * (-0.00157565f +
              t * (0.00916281f + t * (-0.02057706f + t * (0.02635537f +
              t * (-0.01647633f + t * 0.00392377f)))))));
    return p * __expf(x) * rsqrtf(x);
}

// ---------- deapodization 1/c helper ----------
__device__ __forceinline__ float deapod_c(int i, float beta2) {
    float xs = (float)(i - NDIM / 2) * (1.0f / (float)GDIM);
    float p = PI_F * 3.0f * xs;
    float arg = beta2 - p * p;
    float s = sqrtf(fabsf(arg));
    if (arg > 0.0f) return sinhf(s) / s;
    return (s < 1e-12f) ? 1.0f : sinf(s) / s;   // not reached for these params
}

// ---------- Kaiser-Bessel kernel weight ----------
__device__ __forceinline__ float kbw(float d, float beta) {
    if (fabsf(d) > 1.5f) return 0.0f;
    float u = d * (2.0f / 3.0f);
    float t = 1.0f - u * u;
    t = fmaxf(t, 0.0f);
    return bessel_i0f(beta * sqrtf(t));
}

// ---------- 640-point FFT in LDS: 640 = 5 x 128 ----------
// Input : lds[n], natural order (n = 0..639)
// Output: lds[ks], fftshifted spectrum (ks = (k+320)%640)
// Uses lds2 as scratch. Caller must __syncthreads() after.
// blockDim.x == 320.
__device__ __forceinline__ void fft640_core(float2* lds, float2* lds2, int tid) {
    // --- radix-5 stage + inter-stage twiddle: threads 0..127, one per b ---
    if (tid < 128) {
        const int bb = tid;
        float2 xa[5];
#pragma unroll
        for (int a = 0; a < 5; ++a) xa[a] = lds[a * 128 + bb];
        // exp(-2*pi*i*j/5) = c5[j] + i*s5[j]
        const float c5[5] = {1.0f, 0.30901699f, -0.80901699f, -0.80901699f, 0.30901699f};
        const float s5[5] = {0.0f, -0.95105652f, -0.58778525f, 0.58778525f, 0.95105652f};
#pragma unroll
        for (int k1 = 0; k1 < 5; ++k1) {
            float2 acc = xa[0];
#pragma unroll
            for (int a = 1; a < 5; ++a) {
                int j = (a * k1) % 5;
                acc.x += xa[a].x * c5[j] - xa[a].y * s5[j];
                acc.y += xa[a].x * s5[j] + xa[a].y * c5[j];
            }
            // twiddle exp(-2*pi*i * b * k1 / 640)
            float ang = -2.0f * PI_F * (float)(bb * k1) * (1.0f / 640.0f);
            float sw, cw;
            __sincosf(ang, &sw, &cw);
            float2 r;
            r.x = acc.x * cw - acc.y * sw;
            r.y = acc.x * sw + acc.y * cw;
            lds2[k1 * 128 + bb] = r;
        }
    }
    __syncthreads();

    // --- 5 independent 128-point radix-2 DIF FFTs: thread = (f, j) ---
    const int f = tid >> 6;   // sub-FFT 0..4
    const int j = tid & 63;   // butterfly 0..63
    float2* arr = lds2 + f * 128;
#pragma unroll
    for (int h = 64; h >= 1; h >>= 1) {
        int g = j / h;
        int jj = j - g * h;
        int p = g * 2 * h + jj;
        float2 u = arr[p];
        float2 v = arr[p + h];
        float2 s = make_float2(u.x + v.x, u.y + v.y);
        float2 d = make_float2(u.x - v.x, u.y - v.y);
        float ang = -PI_F * (float)jj / (float)h;
        float sw, cw;
        __sincosf(ang, &sw, &cw);
        arr[p] = s;
        arr[p + h] = make_float2(d.x * cw - d.y * sw, d.x * sw + d.y * cw);
        __syncthreads();
    }

    // --- un-bit-reverse + composite reorder (k = k1 + 5*k2) + fftshift, into lds ---
#pragma unroll
    for (int half = 0; half < 2; ++half) {
        int k2 = j + 64 * half;
        int src = f * 128 + (int)(__brev((unsigned)k2) >> 25);
        int k = f + 5 * k2;
        int ks = (k >= 320) ? (k - 320) : (k + 320);
        lds[ks] = lds2[src];
    }
}

// ---------- Pass A: deapod + pad + ifftshift + FFT over x ----------
// One block per (b, y): writes buf1[b][y][kxs] row-contiguous.
__global__ __launch_bounds__(320) void pass_a(const float* __restrict__ x_re,
                                              const float* __restrict__ x_im,
                                              float2* __restrict__ buf1,
                                              float beta2) {
    __shared__ float2 lds[640];
    __shared__ float2 lds2[640];
    const int b = blockIdx.y;
    const int y = blockIdx.x;          // row index of ifftshifted padded image
    const int tid = threadIdx.x;

    const int yy = (y >= 320) ? (y - 320) : (y + 320);   // source row in img_p
    float2* dst = buf1 + ((size_t)b * GDIM + y) * GDIM;

    if (yy < PADW || yy >= PADW + NDIM) {
        // entire row zero -> FFT is zero
        for (int i = tid; i < GDIM; i += 320) dst[i] = make_float2(0.0f, 0.0f);
        return;
    }
    const int ry = yy - PADW;          // 0..319
    const float cy = deapod_c(ry, beta2);
    const float scale = 1.0f / (cy * (float)GDIM);   // fold deapod(y) and 1/G

    for (int i = tid; i < GDIM; i += 320) {
        int xx = (i >= 320) ? (i - 320) : (i + 320);
        float2 v = make_float2(0.0f, 0.0f);
        if (xx >= PADW && xx < PADW + NDIM) {
            int rx = xx - PADW;
            float cx = deapod_c(rx, beta2);
            float sc = scale / cx;
            size_t off = ((size_t)b * NDIM + ry) * NDIM + rx;
            v.x = x_re[off] * sc;
            v.y = x_im[off] * sc;
        }
        lds[i] = v;
    }
    __syncthreads();

    fft640_core(lds, lds2, tid);
    __syncthreads();

    for (int i = tid; i < GDIM; i += 320) dst[i] = lds[i];
}

// ---------- Pass B: FFT over y ----------
// One block per (b, kxs): reads column kxs of buf1, writes kbuf[b][kxs][kys].
__global__ __launch_bounds__(320) void pass_b(const float2* __restrict__ buf1,
                                              float2* __restrict__ kbuf) {
    __shared__ float2 lds[640];
    __shared__ float2 lds2[640];
    const int b = blockIdx.y;
    const int kxs = blockIdx.x;
    const int tid = threadIdx.x;

    for (int i = tid; i < GDIM; i += 320) {
        lds[i] = buf1[((size_t)b * GDIM + i) * GDIM + kxs];
    }
    __syncthreads();

    fft640_core(lds, lds2, tid);
    __syncthreads();

    float2* dst = kbuf + ((size_t)b * GDIM + kxs) * GDIM;
    for (int i = tid; i < GDIM; i += 320) dst[i] = lds[i];
}

// ---------- Gather: 3x3 Kaiser-Bessel interpolation + sqrt(dcf) ----------
__global__ __launch_bounds__(256) void gather_kernel(const float* __restrict__ traj,
                                                     const float* __restrict__ dcf,
                                                     const float2* __restrict__ kbuf,
                                                     float2* __restrict__ out,
                                                     float beta) {
    const int idx = blockIdx.x * blockDim.x + threadIdx.x;
    if (idx >= NB * NM) return;
    const int b = idx / NM;
    const int m = idx - b * NM;

    const float tx = traj[((size_t)b * 2 + 0) * NM + m];
    const float ty = traj[((size_t)b * 2 + 1) * NM + m];
    const float cx = (tx + 0.5f) * (float)GDIM;
    const float cy = (ty + 0.5f) * (float)GDIM;
    const float bx = floorf(cx - 1.0f);
    const float by = floorf(cy - 1.0f);

    float wx[3], wy[3];
    int ix[3], iy[3];
#pragma unroll
    for (int l = 0; l < 3; ++l) {
        float dx = cx - (bx + (float)l);
        float dy = cy - (by + (float)l);
        wx[l] = kbw(dx, beta);
        wy[l] = kbw(dy, beta);
        int i = (int)bx + l;
        i %= GDIM; if (i < 0) i += GDIM;
        ix[l] = i;
        int jj = (int)by + l;
        jj %= GDIM; if (jj < 0) jj += GDIM;
        iy[l] = jj;
    }

    float accx = 0.0f, accy = 0.0f;
#pragma unroll
    for (int lx = 0; lx < 3; ++lx) {
        const float2* row = kbuf + ((size_t)b * GDIM + ix[lx]) * GDIM;
        const float wxl = wx[lx];
#pragma unroll
        for (int ly = 0; ly < 3; ++ly) {
            float w = wy[ly] * wxl;
            float2 v = row[iy[ly]];
            accx += v.x * w;
            accy += v.y * w;
        }
    }
    const float s = sqrtf(dcf[(size_t)b * NM + m]);
    out[idx] = make_float2(accx * s, accy * s);
}

extern "C" void kernel_launch(void* const* d_in, const int* in_sizes, int n_in,
                              void* d_out, int out_size, void* d_ws, size_t ws_size,
                              hipStream_t stream) {
    const float* x_re = (const float*)d_in[0];
    const float* x_im = (const float*)d_in[1];
    const float* traj = (const float*)d_in[2];
    const float* dcf  = (const float*)d_in[3];

    float2* buf1 = (float2*)d_ws;                          // [B][G][G] row-FFT result
    float2* kbuf = buf1 + (size_t)NB * GDIM * GDIM;        // [B][kx][ky] final kgrid^T

    const double beta_d = M_PI * sqrt((1.5 * 1.5) * (1.5 * 1.5) - 0.8);
    const float beta = (float)beta_d;
    const float beta2 = (float)(beta_d * beta_d);

    dim3 gridA(GDIM, NB);
    pass_a<<<gridA, 320, 0, stream>>>(x_re, x_im, buf1, beta2);

    dim3 gridB(GDIM, NB);
    pass_b<<<gridB, 320, 0, stream>>>(buf1, kbuf);

    const int total = NB * NM;
    gather_kernel<<<(total + 255) / 256, 256, 0, stream>>>(traj, dcf, kbuf,
                                                           (float2*)d_out, beta);
}

// Round 2
// 101.646 us; speedup vs baseline: 1.0222x; 1.0222x over previous
//
#include <hip/hip_runtime.h>
#include <math.h>

#define GDIM 640
#define NDIM 320
#define NB 8
#define NM 200000
#define SPT 4
#define PI_F 3.14159265358979323846f

// ---------- Bessel I0 (Abramowitz & Stegun 9.8.1/9.8.2, |err| < 2e-7) ----------
__device__ __forceinline__ float bessel_i0f(float x) {
    if (x < 3.75f) {
        float t = x * (1.0f / 3.75f);
        t *= t;
        return 1.0f + t * (3.5156229f + t * (3.0899424f + t * (1.2067492f +
                     t * (0.2659732f + t * (0.0360768f + t * 0.0045813f)))));
    }
    float t = 3.75f / x;
    float p = 0.39894228f + t * (0.01328592f + t * (0.00225319f + t * (-0.00157565f +
              t * (0.00916281f + t * (-0.02057706f + t * (0.02635537f +
              t * (-0.01647633f + t * 0.00392377f)))))));
    return p * __expf(x) * rsqrtf(x);
}

// ---------- deapodization 1/c helper ----------
__device__ __forceinline__ float deapod_c(int i, float beta2) {
    float xs = (float)(i - NDIM / 2) * (1.0f / (float)GDIM);
    float p = PI_F * 3.0f * xs;
    float arg = beta2 - p * p;
    float s = sqrtf(fabsf(arg));
    if (arg > 0.0f) return sinhf(s) / s;
    return (s < 1e-12f) ? 1.0f : sinf(s) / s;   // not reached for these params
}

// ---------- Kaiser-Bessel kernel weight ----------
__device__ __forceinline__ float kbw(float d, float beta) {
    if (fabsf(d) > 1.5f) return 0.0f;
    float u = d * (2.0f / 3.0f);
    float t = 1.0f - u * u;
    t = fmaxf(t, 0.0f);
    return bessel_i0f(beta * sqrtf(t));
}

// ---------- 640-point FFT in LDS: 640 = 5 x 128 ----------
// Input : lds[n], natural order. Output: lds[ks], fftshifted spectrum.
// blockDim.x == 320. Caller must __syncthreads() after.
__device__ __forceinline__ void fft640_core(float2* lds, float2* lds2, int tid) {
    // --- radix-5 stage + inter-stage twiddle: threads 0..127 ---
    if (tid < 128) {
        const int bb = tid;
        float2 xa[5];
#pragma unroll
        for (int a = 0; a < 5; ++a) xa[a] = lds[a * 128 + bb];
        const float c5[5] = {1.0f, 0.30901699f, -0.80901699f, -0.80901699f, 0.30901699f};
        const float s5[5] = {0.0f, -0.95105652f, -0.58778525f, 0.58778525f, 0.95105652f};
#pragma unroll
        for (int k1 = 0; k1 < 5; ++k1) {
            float2 acc = xa[0];
#pragma unroll
            for (int a = 1; a < 5; ++a) {
                int j = (a * k1) % 5;
                acc.x += xa[a].x * c5[j] - xa[a].y * s5[j];
                acc.y += xa[a].x * s5[j] + xa[a].y * c5[j];
            }
            float ang = -2.0f * PI_F * (float)(bb * k1) * (1.0f / 640.0f);
            float sw, cw;
            __sincosf(ang, &sw, &cw);
            float2 r;
            r.x = acc.x * cw - acc.y * sw;
            r.y = acc.x * sw + acc.y * cw;
            lds2[k1 * 128 + bb] = r;
        }
    }
    __syncthreads();

    // --- 5 independent 128-point radix-2 DIF FFTs ---
    const int f = tid >> 6;
    const int j = tid & 63;
    float2* arr = lds2 + f * 128;
#pragma unroll
    for (int h = 64; h >= 1; h >>= 1) {
        int g = j / h;
        int jj = j - g * h;
        int p = g * 2 * h + jj;
        float2 u = arr[p];
        float2 v = arr[p + h];
        float2 s = make_float2(u.x + v.x, u.y + v.y);
        float2 d = make_float2(u.x - v.x, u.y - v.y);
        float ang = -PI_F * (float)jj / (float)h;
        float sw, cw;
        __sincosf(ang, &sw, &cw);
        arr[p] = s;
        arr[p + h] = make_float2(d.x * cw - d.y * sw, d.x * sw + d.y * cw);
        __syncthreads();
    }

    // --- un-bit-reverse + composite reorder + fftshift ---
#pragma unroll
    for (int half = 0; half < 2; ++half) {
        int k2 = j + 64 * half;
        int src = f * 128 + (int)(__brev((unsigned)k2) >> 25);
        int k = f + 5 * k2;
        int ks = (k >= 320) ? (k - 320) : (k + 320);
        lds[ks] = lds2[src];
    }
}

// ---------- Pass A: deapod + pad + ifftshift + FFT over x (non-zero rows only) ----------
// Compact storage: buf1c[b][r][kxs], r = 0..319 <-> ifftshifted row y = (r<160)? r : r+320.
__global__ __launch_bounds__(320) void pass_a(const float* __restrict__ x_re,
                                              const float* __restrict__ x_im,
                                              float2* __restrict__ buf1c,
                                              float beta2) {
    __shared__ float2 lds[640];
    __shared__ float2 lds2[640];
    const int b = blockIdx.y;
    const int r = blockIdx.x;          // compact row 0..319
    const int tid = threadIdx.x;

    const int ry = (r < 160) ? (r + 160) : (r - 160);   // source image row 0..319
    const float cy = deapod_c(ry, beta2);
    const float scale = 1.0f / (cy * (float)GDIM);

    for (int i = tid; i < GDIM; i += 320) {
        int xx = (i >= 320) ? (i - 320) : (i + 320);
        float2 v = make_float2(0.0f, 0.0f);
        if (xx >= 160 && xx < 480) {
            int rx = xx - 160;
            float cx = deapod_c(rx, beta2);
            float sc = scale / cx;
            size_t off = ((size_t)b * NDIM + ry) * NDIM + rx;
            v.x = x_re[off] * sc;
            v.y = x_im[off] * sc;
        }
        lds[i] = v;
    }
    __syncthreads();

    fft640_core(lds, lds2, tid);
    __syncthreads();

    float2* dst = buf1c + ((size_t)b * NDIM + r) * GDIM;
    for (int i = tid; i < GDIM; i += 320) dst[i] = lds[i];
}

// ---------- Pass B: FFT over y ----------
// XCD-swizzled kxs so the 8 columns sharing each 64B line stay on one XCD's L2.
__global__ __launch_bounds__(320) void pass_b(const float2* __restrict__ buf1c,
                                              float2* __restrict__ kbuf) {
    __shared__ float2 lds[640];
    __shared__ float2 lds2[640];
    const int b = blockIdx.y;
    const int raw = blockIdx.x;
    const int kxs = (raw & 7) * 80 + (raw >> 3);
    const int tid = threadIdx.x;

    for (int i = tid; i < GDIM; i += 320) {
        float2 v = make_float2(0.0f, 0.0f);
        int yc = (i < 160) ? i : ((i >= 480) ? (i - 320) : -1);
        if (yc >= 0) v = buf1c[((size_t)b * NDIM + yc) * GDIM + kxs];
        lds[i] = v;
    }
    __syncthreads();

    fft640_core(lds, lds2, tid);
    __syncthreads();

    float2* dst = kbuf + ((size_t)b * GDIM + kxs) * GDIM;
    for (int i = tid; i < GDIM; i += 320) dst[i] = lds[i];
}

// ---------- Gather: 3x3 KB interpolation + sqrt(dcf), 4 samples/thread ----------
__global__ __launch_bounds__(256) void gather_kernel(const float* __restrict__ traj,
                                                     const float* __restrict__ dcf,
                                                     const float2* __restrict__ kbuf,
                                                     float2* __restrict__ out,
                                                     float beta) {
    const int t = blockIdx.x * 256 + threadIdx.x;
    const int per_b = NM / SPT;                 // 50000
    if (t >= NB * per_b) return;
    const int b = t / per_b;
    const int m0 = (t - b * per_b) * SPT;

    const float4 txv = *(const float4*)(traj + ((size_t)b * 2 + 0) * NM + m0);
    const float4 tyv = *(const float4*)(traj + ((size_t)b * 2 + 1) * NM + m0);
    const float4 dcv = *(const float4*)(dcf + (size_t)b * NM + m0);
    const float2* __restrict__ kb = kbuf + (size_t)b * GDIM * GDIM;

    float2 val[SPT][9];
    float fx[SPT], fy[SPT];

    // ---- phase 1: addresses + issue all 36 scattered loads ----
#pragma unroll
    for (int s = 0; s < SPT; ++s) {
        const float tx = (s == 0) ? txv.x : (s == 1) ? txv.y : (s == 2) ? txv.z : txv.w;
        const float ty = (s == 0) ? tyv.x : (s == 1) ? tyv.y : (s == 2) ? tyv.z : tyv.w;
        const float cx = (tx + 0.5f) * (float)GDIM;
        const float cy = (ty + 0.5f) * (float)GDIM;
        const int bxi = (int)floorf(cx - 1.0f);
        const int byi = (int)floorf(cy - 1.0f);
        fx[s] = cx - (float)bxi;               // d at tap 0, in [1,2)
        fy[s] = cy - (float)byi;

        int iy[3];
#pragma unroll
        for (int l = 0; l < 3; ++l) {
            int v = byi + l;
            if (v < 0) v += GDIM; else if (v >= GDIM) v -= GDIM;
            iy[l] = v;
        }
#pragma unroll
        for (int lx = 0; lx < 3; ++lx) {
            int v = bxi + lx;
            if (v < 0) v += GDIM; else if (v >= GDIM) v -= GDIM;
            const float2* row = kb + (size_t)v * GDIM;
#pragma unroll
            for (int ly = 0; ly < 3; ++ly) {
                val[s][lx * 3 + ly] = row[iy[ly]];
            }
        }
    }

    // ---- phase 2: weights + accumulate (loads still in flight above) ----
    float2 res[SPT];
#pragma unroll
    for (int s = 0; s < SPT; ++s) {
        float wx[3], wy[3];
#pragma unroll
        for (int l = 0; l < 3; ++l) {
            wx[l] = kbw(fx[s] - (float)l, beta);
            wy[l] = kbw(fy[s] - (float)l, beta);
        }
        float ax = 0.0f, ay = 0.0f;
#pragma unroll
        for (int lx = 0; lx < 3; ++lx) {
#pragma unroll
            for (int ly = 0; ly < 3; ++ly) {
                const float w = wx[lx] * wy[ly];
                const float2 v = val[s][lx * 3 + ly];
                ax += v.x * w;
                ay += v.y * w;
            }
        }
        const float dc = (s == 0) ? dcv.x : (s == 1) ? dcv.y : (s == 2) ? dcv.z : dcv.w;
        const float sc = sqrtf(dc);
        res[s] = make_float2(ax * sc, ay * sc);
    }

    float4* op = (float4*)(out + (size_t)b * NM + m0);
    op[0] = make_float4(res[0].x, res[0].y, res[1].x, res[1].y);
    op[1] = make_float4(res[2].x, res[2].y, res[3].x, res[3].y);
}

extern "C" void kernel_launch(void* const* d_in, const int* in_sizes, int n_in,
                              void* d_out, int out_size, void* d_ws, size_t ws_size,
                              hipStream_t stream) {
    const float* x_re = (const float*)d_in[0];
    const float* x_im = (const float*)d_in[1];
    const float* traj = (const float*)d_in[2];
    const float* dcf  = (const float*)d_in[3];

    float2* buf1c = (float2*)d_ws;                          // [B][320][640] row-FFT (non-zero rows)
    float2* kbuf  = buf1c + (size_t)NB * NDIM * GDIM;       // [B][kx][ky] kgrid^T

    const double beta_d = M_PI * sqrt((1.5 * 1.5) * (1.5 * 1.5) - 0.8);
    const float beta = (float)beta_d;
    const float beta2 = (float)(beta_d * beta_d);

    dim3 gridA(NDIM, NB);
    pass_a<<<gridA, 320, 0, stream>>>(x_re, x_im, buf1c, beta2);

    dim3 gridB(GDIM, NB);
    pass_b<<<gridB, 320, 0, stream>>>(buf1c, kbuf);

    const int total4 = NB * (NM / SPT);
    gather_kernel<<<(total4 + 255) / 256, 256, 0, stream>>>(traj, dcf, kbuf,
                                                            (float2*)d_out, beta);
}

// Round 3
// 78.247 us; speedup vs baseline: 1.3279x; 1.2990x over previous
//
#include <hip/hip_runtime.h>
#include <math.h>

#define GDIM 640
#define NDIM 320
#define NB 8
#define NM 200000
#define PI_F 3.14159265358979323846f

// ---------- Bessel I0 (Abramowitz & Stegun 9.8.1/9.8.2, |err| < 2e-7) ----------
__device__ __forceinline__ float bessel_i0f(float x) {
    if (x < 3.75f) {
        float t = x * (1.0f / 3.75f);
        t *= t;
        return 1.0f + t * (3.5156229f + t * (3.0899424f + t * (1.2067492f +
                     t * (0.2659732f + t * (0.0360768f + t * 0.0045813f)))));
    }
    float t = 3.75f / x;
    float p = 0.39894228f + t * (0.01328592f + t * (0.00225319f + t * (-0.00157565f +
              t * (0.00916281f + t * (-0.02057706f + t * (0.02635537f +
              t * (-0.01647633f + t * 0.00392377f)))))));
    return p * __expf(x) * rsqrtf(x);
}

// ---------- deapodization 1/c helper ----------
__device__ __forceinline__ float deapod_c(int i, float beta2) {
    float xs = (float)(i - NDIM / 2) * (1.0f / (float)GDIM);
    float p = PI_F * 3.0f * xs;
    float arg = beta2 - p * p;
    float s = sqrtf(fabsf(arg));
    if (arg > 0.0f) return sinhf(s) / s;
    return (s < 1e-12f) ? 1.0f : sinf(s) / s;   // not reached for these params
}

// ---------- Kaiser-Bessel kernel weight ----------
__device__ __forceinline__ float kbw(float d, float beta) {
    if (fabsf(d) > 1.5f) return 0.0f;
    float u = d * (2.0f / 3.0f);
    float t = 1.0f - u * u;
    t = fmaxf(t, 0.0f);
    return bessel_i0f(beta * sqrtf(t));
}

// ---------- 640-point FFT in LDS: 640 = 5 x 128 ----------
// Input : lds[n], natural order. Output: lds[ks], fftshifted spectrum.
// blockDim.x == 320. Caller must __syncthreads() after.
__device__ __forceinline__ void fft640_core(float2* lds, float2* lds2, int tid) {
    // --- radix-5 stage + inter-stage twiddle: threads 0..127 ---
    if (tid < 128) {
        const int bb = tid;
        float2 xa[5];
#pragma unroll
        for (int a = 0; a < 5; ++a) xa[a] = lds[a * 128 + bb];
        const float c5[5] = {1.0f, 0.30901699f, -0.80901699f, -0.80901699f, 0.30901699f};
        const float s5[5] = {0.0f, -0.95105652f, -0.58778525f, 0.58778525f, 0.95105652f};
#pragma unroll
        for (int k1 = 0; k1 < 5; ++k1) {
            float2 acc = xa[0];
#pragma unroll
            for (int a = 1; a < 5; ++a) {
                int j = (a * k1) % 5;
                acc.x += xa[a].x * c5[j] - xa[a].y * s5[j];
                acc.y += xa[a].x * s5[j] + xa[a].y * c5[j];
            }
            float ang = -2.0f * PI_F * (float)(bb * k1) * (1.0f / 640.0f);
            float sw, cw;
            __sincosf(ang, &sw, &cw);
            float2 r;
            r.x = acc.x * cw - acc.y * sw;
            r.y = acc.x * sw + acc.y * cw;
            lds2[k1 * 128 + bb] = r;
        }
    }
    __syncthreads();

    // --- 5 independent 128-point radix-2 DIF FFTs ---
    const int f = tid >> 6;
    const int j = tid & 63;
    float2* arr = lds2 + f * 128;
#pragma unroll
    for (int h = 64; h >= 1; h >>= 1) {
        int g = j / h;
        int jj = j - g * h;
        int p = g * 2 * h + jj;
        float2 u = arr[p];
        float2 v = arr[p + h];
        float2 s = make_float2(u.x + v.x, u.y + v.y);
        float2 d = make_float2(u.x - v.x, u.y - v.y);
        float ang = -PI_F * (float)jj / (float)h;
        float sw, cw;
        __sincosf(ang, &sw, &cw);
        arr[p] = s;
        arr[p + h] = make_float2(d.x * cw - d.y * sw, d.x * sw + d.y * cw);
        __syncthreads();
    }

    // --- un-bit-reverse + composite reorder + fftshift ---
#pragma unroll
    for (int half = 0; half < 2; ++half) {
        int k2 = j + 64 * half;
        int src = f * 128 + (int)(__brev((unsigned)k2) >> 25);
        int k = f + 5 * k2;
        int ks = (k >= 320) ? (k - 320) : (k + 320);
        lds[ks] = lds2[src];
    }
}

// ---------- Pass A: deapod + pad + ifftshift + FFT over x (non-zero rows only) ----------
// Compact storage: buf1c[b][r][kxs], r = 0..319 <-> ifftshifted row y = (r<160)? r : r+320.
__global__ __launch_bounds__(320) void pass_a(const float* __restrict__ x_re,
                                              const float* __restrict__ x_im,
                                              float2* __restrict__ buf1c,
                                              float beta2) {
    __shared__ float2 lds[640];
    __shared__ float2 lds2[640];
    const int b = blockIdx.y;
    const int r = blockIdx.x;          // compact row 0..319
    const int tid = threadIdx.x;

    const int ry = (r < 160) ? (r + 160) : (r - 160);   // source image row 0..319
    const float cy = deapod_c(ry, beta2);
    const float scale = 1.0f / (cy * (float)GDIM);

    for (int i = tid; i < GDIM; i += 320) {
        int xx = (i >= 320) ? (i - 320) : (i + 320);
        float2 v = make_float2(0.0f, 0.0f);
        if (xx >= 160 && xx < 480) {
            int rx = xx - 160;
            float cx = deapod_c(rx, beta2);
            float sc = scale / cx;
            size_t off = ((size_t)b * NDIM + ry) * NDIM + rx;
            v.x = x_re[off] * sc;
            v.y = x_im[off] * sc;
        }
        lds[i] = v;
    }
    __syncthreads();

    fft640_core(lds, lds2, tid);
    __syncthreads();

    float2* dst = buf1c + ((size_t)b * NDIM + r) * GDIM;
    for (int i = tid; i < GDIM; i += 320) dst[i] = lds[i];
}

// ---------- Pass B: FFT over y ----------
// XCD-swizzled kxs so the 8 columns sharing each 64B line stay on one XCD's L2.
__global__ __launch_bounds__(320) void pass_b(const float2* __restrict__ buf1c,
                                              float2* __restrict__ kbuf) {
    __shared__ float2 lds[640];
    __shared__ float2 lds2[640];
    const int b = blockIdx.y;
    const int raw = blockIdx.x;
    const int kxs = (raw & 7) * 80 + (raw >> 3);
    const int tid = threadIdx.x;

    for (int i = tid; i < GDIM; i += 320) {
        float2 v = make_float2(0.0f, 0.0f);
        int yc = (i < 160) ? i : ((i >= 480) ? (i - 320) : -1);
        if (yc >= 0) v = buf1c[((size_t)b * NDIM + yc) * GDIM + kxs];
        lds[i] = v;
    }
    __syncthreads();

    fft640_core(lds, lds2, tid);
    __syncthreads();

    float2* dst = kbuf + ((size_t)b * GDIM + kxs) * GDIM;
    for (int i = tid; i < GDIM; i += 320) dst[i] = lds[i];
}

// ---------- Gather: 3x3 KB interpolation + sqrt(dcf), 1 sample/thread ----------
// Block -> XCD partitioning: b = blockIdx.x & 7 so each XCD's L2 caches only
// its own batch's kbuf slice (3.3 MB < 4 MB L2).
#define GBLK_PER_B ((NM + 255) / 256)      // 782
__global__ __launch_bounds__(256) void gather_kernel(const float* __restrict__ traj,
                                                     const float* __restrict__ dcf,
                                                     const float2* __restrict__ kbuf,
                                                     float2* __restrict__ out,
                                                     float beta) {
    const int bid = blockIdx.x;
    const int b = bid & 7;
    const int m = (bid >> 3) * 256 + threadIdx.x;
    if (m >= NM) return;

    const float tx = traj[((size_t)b * 2 + 0) * NM + m];
    const float ty = traj[((size_t)b * 2 + 1) * NM + m];
    const float cx = (tx + 0.5f) * (float)GDIM;
    const float cy = (ty + 0.5f) * (float)GDIM;
    const float bx = floorf(cx - 1.0f);
    const float by = floorf(cy - 1.0f);

    float wx[3], wy[3];
    int ix[3], iy[3];
#pragma unroll
    for (int l = 0; l < 3; ++l) {
        float dx = cx - (bx + (float)l);
        float dy = cy - (by + (float)l);
        wx[l] = kbw(dx, beta);
        wy[l] = kbw(dy, beta);
        int i = (int)bx + l;
        i %= GDIM; if (i < 0) i += GDIM;
        ix[l] = i;
        int jj = (int)by + l;
        jj %= GDIM; if (jj < 0) jj += GDIM;
        iy[l] = jj;
    }

    float accx = 0.0f, accy = 0.0f;
#pragma unroll
    for (int lx = 0; lx < 3; ++lx) {
        const float2* row = kbuf + ((size_t)b * GDIM + ix[lx]) * GDIM;
        const float wxl = wx[lx];
#pragma unroll
        for (int ly = 0; ly < 3; ++ly) {
            float w = wy[ly] * wxl;
            float2 v = row[iy[ly]];
            accx += v.x * w;
            accy += v.y * w;
        }
    }
    const float s = sqrtf(dcf[(size_t)b * NM + m]);
    out[(size_t)b * NM + m] = make_float2(accx * s, accy * s);
}

extern "C" void kernel_launch(void* const* d_in, const int* in_sizes, int n_in,
                              void* d_out, int out_size, void* d_ws, size_t ws_size,
                              hipStream_t stream) {
    const float* x_re = (const float*)d_in[0];
    const float* x_im = (const float*)d_in[1];
    const float* traj = (const float*)d_in[2];
    const float* dcf  = (const float*)d_in[3];

    float2* buf1c = (float2*)d_ws;                          // [B][320][640] row-FFT (non-zero rows)
    float2* kbuf  = buf1c + (size_t)NB * NDIM * GDIM;       // [B][kx][ky] kgrid^T

    const double beta_d = M_PI * sqrt((1.5 * 1.5) * (1.5 * 1.5) - 0.8);
    const float beta = (float)beta_d;
    const float beta2 = (float)(beta_d * beta_d);

    dim3 gridA(NDIM, NB);
    pass_a<<<gridA, 320, 0, stream>>>(x_re, x_im, buf1c, beta2);

    dim3 gridB(GDIM, NB);
    pass_b<<<gridB, 320, 0, stream>>>(buf1c, kbuf);

    gather_kernel<<<GBLK_PER_B * NB, 256, 0, stream>>>(traj, dcf, kbuf,
                                                       (float2*)d_out, beta);
}